// Round 1
// baseline (400.669 us; speedup 1.0000x reference)
//
#include <hip/hip_runtime.h>

// BatchedSequences: scatter concatenated (T,F) rows into padded (B,max_sl,F),
// zero-filling the tail of each batch row. Pure HBM-streaming kernel.
//
// Shapes (fixed by setup_inputs): B=32, F=512, MAX_SL=4096, T=99328.
// Traffic: read 203 MB + write 268 MB => ~75us floor at 6.3 TB/s.

constexpr int F_DIM  = 512;
constexpr int FV     = F_DIM / 4;   // 128 float4 per feature row
constexpr int FV_SH  = 7;           // log2(FV)
constexpr int MAX_SL = 4096;
constexpr int SL_SH  = 12;          // log2(MAX_SL)
constexpr int B_MAX  = 64;          // LDS capacity headroom (actual B=32)

__global__ __launch_bounds__(256) void pad_scatter(
    const float4* __restrict__ S,   // (T, FV) float4
    const int*    __restrict__ L,   // (B,) int32 lengths
    float4*       __restrict__ out, // (B, MAX_SL, FV) float4
    int B, int total_v4)
{
    __shared__ int s_len[B_MAX];
    __shared__ int s_off[B_MAX];

    // Stage lengths + per-batch row offsets into LDS (first wave only).
    if (threadIdx.x < B) s_len[threadIdx.x] = L[threadIdx.x];
    __syncthreads();
    if (threadIdx.x < B) {
        int acc = 0;
        for (int b = 0; b < (int)threadIdx.x; ++b) acc += s_len[b];
        s_off[threadIdx.x] = acc;
    }
    __syncthreads();

    const int stride = gridDim.x * blockDim.x;
    for (int idx = blockIdx.x * blockDim.x + threadIdx.x; idx < total_v4;
         idx += stride) {
        const int col = idx & (FV - 1);
        const int row = idx >> FV_SH;       // flat output row in (B*MAX_SL)
        const int b   = row >> SL_SH;       // batch index
        const int p   = row & (MAX_SL - 1); // position within batch row

        float4 v = make_float4(0.f, 0.f, 0.f, 0.f);
        if (p < s_len[b]) {
            v = S[(size_t)(s_off[b] + p) * FV + col];
        }
        out[idx] = v;
    }
}

extern "C" void kernel_launch(void* const* d_in, const int* in_sizes, int n_in,
                              void* d_out, int out_size, void* d_ws, size_t ws_size,
                              hipStream_t stream) {
    const float4* S = (const float4*)d_in[0];
    const int*    L = (const int*)d_in[1];
    float4*       out = (float4*)d_out;

    const int B        = in_sizes[1];       // 32
    const int total_v4 = out_size / 4;      // 32*4096*512/4 = 16,777,216

    // 2048 blocks x 256 threads: 524288 threads, 32 float4 (512 B) each.
    // Amortizes the per-block LDS offset setup; saturates all 256 CUs.
    pad_scatter<<<2048, 256, 0, stream>>>(S, L, out, B, total_v4);
}

// Round 3
// 395.382 us; speedup vs baseline: 1.0134x; 1.0134x over previous
//
#include <hip/hip_runtime.h>

// BatchedSequences: scatter concatenated (T,F) fp32 rows into padded
// (B, MAX_SL, F), zero-filling tails. Pure one-pass HBM stream:
// read 203 MB + write 268 MB => ~75 us floor at 6.3 TB/s.
//
// Fixed shapes (setup_inputs): B=32, F=512, MAX_SL=4096, T=99328.
//
// Structure: 524288 threads (2048x256) = exactly one batch's worth of
// float4s (4096 rows x 128 v4-cols), so each thread keeps ONE (p, col)
// pair and walks all 32 batches with compile-time-constant strides.
// Loads batched 4-deep ahead of stores (MLP); nontemporal since this is
// a one-pass stream with zero reuse.
//
// Note: HIP float4 is a struct — __builtin_nontemporal_* needs a native
// clang vector type, hence the ext_vector_type alias.

typedef float vf4 __attribute__((ext_vector_type(4)));

constexpr int B_N     = 32;
constexpr int FV      = 128;               // 512 floats = 128 vf4
constexpr int THREADS = 256;
constexpr int BLOCKS  = 2048;
constexpr int NTHREAD = BLOCKS * THREADS;  // 524288 = MAX_SL * FV (one batch)

__global__ __launch_bounds__(THREADS) void pad_scatter(
    const vf4* __restrict__ S,   // (T, FV)
    const int* __restrict__ L,   // (B,)
    vf4*       __restrict__ out) // (B, MAX_SL, FV)
{
    __shared__ int s_len[B_N];
    __shared__ int s_off[B_N];

    if (threadIdx.x < B_N) s_len[threadIdx.x] = L[threadIdx.x];
    __syncthreads();
    if (threadIdx.x < B_N) {
        int acc = 0;
        for (int b = 0; b < (int)threadIdx.x; ++b) acc += s_len[b];
        s_off[threadIdx.x] = acc;
    }
    __syncthreads();

    const int base = blockIdx.x * THREADS + threadIdx.x; // [0, NTHREAD)
    const int col  = base & (FV - 1);
    const int p    = base >> 7;                          // row within batch

    #pragma unroll
    for (int b0 = 0; b0 < B_N; b0 += 4) {
        vf4 v[4];
        // Issue all 4 loads before any store (branches are wave-uniform:
        // all 64 lanes of a wave share the same p).
        #pragma unroll
        for (int j = 0; j < 4; ++j) {
            const int b = b0 + j;
            v[j] = (vf4)(0.f);
            if (p < s_len[b]) {
                v[j] = __builtin_nontemporal_load(
                    &S[(size_t)(s_off[b] + p) * FV + col]);
            }
        }
        #pragma unroll
        for (int j = 0; j < 4; ++j) {
            __builtin_nontemporal_store(
                v[j], &out[(size_t)(b0 + j) * NTHREAD + base]);
        }
    }
}

extern "C" void kernel_launch(void* const* d_in, const int* in_sizes, int n_in,
                              void* d_out, int out_size, void* d_ws, size_t ws_size,
                              hipStream_t stream) {
    const vf4* S   = (const vf4*)d_in[0];
    const int* L   = (const int*)d_in[1];
    vf4*       out = (vf4*)d_out;

    pad_scatter<<<BLOCKS, THREADS, 0, stream>>>(S, L, out);
}